// Round 3
// baseline (511.101 us; speedup 1.0000x reference)
//
#include <hip/hip_runtime.h>
#include <hip/hip_bf16.h>

// Problem constants
#define NN 8192   // nodes
#define KD 256    // feature size (GEMM K)

typedef __bf16 bf16x8 __attribute__((ext_vector_type(8)));
typedef float  f32x4  __attribute__((ext_vector_type(4)));
typedef int    i32x4  __attribute__((ext_vector_type(4)));

union frag_u { i32x4 i; bf16x8 b; };

// ---------------------------------------------------------------------------
// Workspace layout (total 4,260,352 B ~= 4.06 MB -- keep small: ws_size may be
// as little as 8 MB; the round-2 failure was summed/inv at ws+8MB overflowing
// into harness buffers and corrupting the pristine-input copies).
//   G      bf16[NN][KD]   at 0        (4 MB)   G[i][s] = sqrt(|wq_s wk_s|) f_si
//   summed f32[NN]        at 4MB      (32 KB)
//   inv    f32[NN]        at 4MB+32K  (32 KB)
//   smask  u32[KD/2]      at 4MB+64K  (512 B)  bf16-pair sign masks of w_s
// ---------------------------------------------------------------------------
#define G_OFF      0
#define SUM_OFF    (4u * 1024 * 1024)
#define INV_OFF    (SUM_OFF + 32u * 1024)
#define SMASK_OFF  (INV_OFF + 32u * 1024)

// ---------------------------------------------------------------------------
// Stage a 128-row x 64-col bf16 tile (16 KB) from row-major [*, 256] source
// into LDS via global_load_lds width=16. T2 XOR swizzle applied on the global
// source side (m173 pattern); swizzle is 16B-granular so lane segments stay
// contiguous.
// ---------------------------------------------------------------------------
__device__ __forceinline__ void stage_tile(const char* src00, char* lds,
                                           int wave, int lane) {
#pragma unroll
  for (int c = 0; c < 4; ++c) {
    const int chunk = ((wave << 2) + c) << 10;       // 1 KB per wave-call
    const int o     = chunk + (lane << 4);
    const int row   = o >> 7;
    const int swb   = o & 127;
    const int colb  = swb ^ ((row & 7) << 4);        // inverse swizzle on source
    __builtin_amdgcn_global_load_lds(
        (const __attribute__((address_space(1))) void*)(src00 + (size_t)row * (KD * 2) + colb),
        (__attribute__((address_space(3))) void*)(lds + chunk),  // wave-uniform base
        16, 0, 0);
  }
}

__device__ __forceinline__ bf16x8 read_frag(const char* lds, int row, int colb) {
  const int addr = (row << 7) + (colb ^ ((row & 7) << 4));
  return *(const bf16x8*)(lds + addr);   // ds_read_b128
}

// B-side fragment with sign(w_s) applied via bf16 sign-bit XOR.
__device__ __forceinline__ bf16x8 read_frag_sgn(const char* lds, int row, int colb,
                                                i32x4 msk) {
  const int addr = (row << 7) + (colb ^ ((row & 7) << 4));
  frag_u u;
  u.i = *(const i32x4*)(lds + addr) ^ msk;
  return u.b;
}

// ---------------------------------------------------------------------------
// prep: G[i][s] = bf16( sqrt(|wq_s*wk_s|) * f[s][i] )   (transposed)
// ---------------------------------------------------------------------------
__global__ void prep_kernel(const float* __restrict__ f,
                            const float* __restrict__ wq,
                            const float* __restrict__ wk,
                            __hip_bfloat16* __restrict__ G) {
  __shared__ float tile[32][33];
  const int i0 = blockIdx.x * 32;
  const int s0 = blockIdx.y * 32;
  const int tx = threadIdx.x, ty = threadIdx.y;   // block (32, 8)
#pragma unroll
  for (int k = 0; k < 4; ++k) {
    const int s = s0 + ty + k * 8;
    tile[ty + k * 8][tx] = f[(size_t)s * NN + i0 + tx];
  }
  __syncthreads();
  const float w  = wq[s0 + tx] * wk[s0 + tx];
  const float sq = sqrtf(fabsf(w));
#pragma unroll
  for (int k = 0; k < 4; ++k) {
    const int ii = ty + k * 8;
    G[(size_t)(i0 + ii) * KD + s0 + tx] = __float2bfloat16(sq * tile[tx][ii]);
  }
}

// ---------------------------------------------------------------------------
// init: zero summed; block 0 also builds the bf16-pair sign masks of w.
// ---------------------------------------------------------------------------
__global__ void init_kernel(const float* __restrict__ wq,
                            const float* __restrict__ wk,
                            float* __restrict__ summed,
                            unsigned* __restrict__ smask) {
  const int j = blockIdx.x * 256 + threadIdx.x;
  summed[j] = 0.0f;
  if (blockIdx.x == 0 && threadIdx.x < KD / 2) {
    const int t = threadIdx.x;
    const float w0 = wq[2 * t] * wk[2 * t];
    const float w1 = wq[2 * t + 1] * wk[2 * t + 1];
    unsigned m = 0;
    if (w0 < 0.0f) m |= 0x00008000u;
    if (w1 < 0.0f) m |= 0x80000000u;
    smask[t] = m;
  }
}

// ---------------------------------------------------------------------------
// sum_kernel: summed[i] += sum_j exp(C[i,j]) * (nbr[i,j] != 0)
// grid: 64 row-strips x 16 col-chunks (4 tiles of 128 cols per chunk)
// ---------------------------------------------------------------------------
__global__ __launch_bounds__(256, 2)
void sum_kernel(const __hip_bfloat16* __restrict__ G,
                const unsigned* __restrict__ smask,
                const int* __restrict__ nbr,
                float* __restrict__ summed) {
  __shared__ __attribute__((aligned(128))) char lA[16384];
  __shared__ __attribute__((aligned(128))) char lB[16384];
  __shared__ __attribute__((aligned(16))) unsigned smem_mask[KD / 2];
  const int lane = threadIdx.x & 63;
  const int wave = threadIdx.x >> 6;
  const int wr = wave >> 1, wc = wave & 1;
  const int strip = blockIdx.x >> 4;   // 0..63
  const int chunk = blockIdx.x & 15;   // 0..15
  const int row0 = strip * 128;

  if (threadIdx.x < KD / 2) smem_mask[threadIdx.x] = smask[threadIdx.x];

  float rsum[4][4] = {};

  for (int t = 0; t < 4; ++t) {
    const int col0 = (chunk * 4 + t) * 128;
    f32x4 acc[4][4] = {{}};
#pragma unroll
    for (int kk = 0; kk < KD; kk += 64) {
      stage_tile((const char*)G + (size_t)row0 * (KD * 2) + kk * 2, lA, wave, lane);
      stage_tile((const char*)G + (size_t)col0 * (KD * 2) + kk * 2, lB, wave, lane);
      asm volatile("s_waitcnt vmcnt(0)" ::: "memory");
      __syncthreads();
#pragma unroll
      for (int kh = 0; kh < 2; ++kh) {
        const int colb = kh * 64 + ((lane >> 4) << 4);
        const i32x4 msk = *(const i32x4*)&smem_mask[(kk >> 1) + kh * 16 + ((lane >> 4) << 2)];
        bf16x8 a[4], b[4];
#pragma unroll
        for (int m = 0; m < 4; ++m) a[m] = read_frag(lA, wr * 64 + m * 16 + (lane & 15), colb);
#pragma unroll
        for (int n = 0; n < 4; ++n) b[n] = read_frag_sgn(lB, wc * 64 + n * 16 + (lane & 15), colb, msk);
#pragma unroll
        for (int m = 0; m < 4; ++m)
#pragma unroll
          for (int n = 0; n < 4; ++n)
            acc[m][n] = __builtin_amdgcn_mfma_f32_16x16x32_bf16(a[m], b[n], acc[m][n], 0, 0, 0);
      }
      __syncthreads();
    }
    // masked exp accumulate; C/D layout: col = lane&15, row = (lane>>4)*4 + r
    const int roww = row0 + wr * 64;
    const int colw = col0 + wc * 64;
#pragma unroll
    for (int n = 0; n < 4; ++n) {
      const int col = colw + n * 16 + (lane & 15);
#pragma unroll
      for (int m = 0; m < 4; ++m) {
        const int rb = roww + m * 16 + ((lane >> 4) << 2);
#pragma unroll
        for (int r = 0; r < 4; ++r) {
          const int mk = nbr[(size_t)(rb + r) * NN + col];
          rsum[m][r] += (mk != 0) ? __expf(acc[m][n][r]) : 0.0f;
        }
      }
    }
  }
  // reduce across the 16 col-lanes, then one atomic per row
#pragma unroll
  for (int m = 0; m < 4; ++m)
#pragma unroll
    for (int r = 0; r < 4; ++r) {
      float v = rsum[m][r];
      v += __shfl_xor(v, 1);
      v += __shfl_xor(v, 2);
      v += __shfl_xor(v, 4);
      v += __shfl_xor(v, 8);
      if ((lane & 15) == 0)
        atomicAdd(&summed[row0 + wr * 64 + m * 16 + ((lane >> 4) << 2) + r], v);
    }
}

// ---------------------------------------------------------------------------
__global__ void inv_kernel(const float* __restrict__ summed, float* __restrict__ inv) {
  const int j = blockIdx.x * 256 + threadIdx.x;
  inv[j] = 1.0f / summed[j];
}

// ---------------------------------------------------------------------------
// out_kernel: out[i,j] = exp(C[i,j]) * inv[j]
// ---------------------------------------------------------------------------
__global__ __launch_bounds__(256, 2)
void out_kernel(const __hip_bfloat16* __restrict__ G,
                const unsigned* __restrict__ smask,
                const float* __restrict__ inv,
                float* __restrict__ out) {
  __shared__ __attribute__((aligned(128))) char lA[16384];
  __shared__ __attribute__((aligned(128))) char lB[16384];
  __shared__ __attribute__((aligned(16))) unsigned smem_mask[KD / 2];
  const int lane = threadIdx.x & 63;
  const int wave = threadIdx.x >> 6;
  const int wr = wave >> 1, wc = wave & 1;

  if (threadIdx.x < KD / 2) smem_mask[threadIdx.x] = smask[threadIdx.x];

  // bijective XCD swizzle (gridDim 4096, divisible by 8)
  const int nwg = gridDim.x;
  const int b = (blockIdx.x & 7) * (nwg >> 3) + (blockIdx.x >> 3);
  const int bm = b >> 6;   // 64 row tiles
  const int bn = b & 63;   // 64 col tiles

  f32x4 acc[4][4] = {{}};
#pragma unroll
  for (int kk = 0; kk < KD; kk += 64) {
    stage_tile((const char*)G + (size_t)(bm * 128) * (KD * 2) + kk * 2, lA, wave, lane);
    stage_tile((const char*)G + (size_t)(bn * 128) * (KD * 2) + kk * 2, lB, wave, lane);
    asm volatile("s_waitcnt vmcnt(0)" ::: "memory");
    __syncthreads();
#pragma unroll
    for (int kh = 0; kh < 2; ++kh) {
      const int colb = kh * 64 + ((lane >> 4) << 4);
      const i32x4 msk = *(const i32x4*)&smem_mask[(kk >> 1) + kh * 16 + ((lane >> 4) << 2)];
      bf16x8 a[4], bfr[4];
#pragma unroll
      for (int m = 0; m < 4; ++m) a[m] = read_frag(lA, wr * 64 + m * 16 + (lane & 15), colb);
#pragma unroll
      for (int n = 0; n < 4; ++n) bfr[n] = read_frag_sgn(lB, wc * 64 + n * 16 + (lane & 15), colb, msk);
#pragma unroll
      for (int m = 0; m < 4; ++m)
#pragma unroll
        for (int n = 0; n < 4; ++n)
          acc[m][n] = __builtin_amdgcn_mfma_f32_16x16x32_bf16(a[m], bfr[n], acc[m][n], 0, 0, 0);
    }
    __syncthreads();
  }

  const int row0 = bm * 128 + wr * 64;
  const int col0 = bn * 128 + wc * 64;
#pragma unroll
  for (int n = 0; n < 4; ++n) {
    const int col = col0 + n * 16 + (lane & 15);
    const float is = inv[col];
#pragma unroll
    for (int m = 0; m < 4; ++m) {
      const int rb = row0 + m * 16 + ((lane >> 4) << 2);
#pragma unroll
      for (int r = 0; r < 4; ++r) {
        out[(size_t)(rb + r) * NN + col] = __expf(acc[m][n][r]) * is;
      }
    }
  }
}

// ---------------------------------------------------------------------------
extern "C" void kernel_launch(void* const* d_in, const int* in_sizes, int n_in,
                              void* d_out, int out_size, void* d_ws, size_t ws_size,
                              hipStream_t stream) {
  const float* f  = (const float*)d_in[0];
  const float* wq = (const float*)d_in[1];
  const float* wk = (const float*)d_in[2];
  const int*   nbr = (const int*)d_in[3];
  float* out = (float*)d_out;

  char* ws = (char*)d_ws;
  __hip_bfloat16* G = (__hip_bfloat16*)(ws + G_OFF);
  float* summed     = (float*)(ws + SUM_OFF);
  float* inv        = (float*)(ws + INV_OFF);
  unsigned* smask   = (unsigned*)(ws + SMASK_OFF);

  prep_kernel<<<dim3(NN / 32, KD / 32), dim3(32, 8), 0, stream>>>(f, wq, wk, G);
  init_kernel<<<NN / 256, 256, 0, stream>>>(wq, wk, summed, smask);
  sum_kernel<<<1024, 256, 0, stream>>>(G, smask, nbr, summed);
  inv_kernel<<<NN / 256, 256, 0, stream>>>(summed, inv);
  out_kernel<<<4096, 256, 0, stream>>>(G, smask, inv, out);
}